// Round 1
// baseline (569.444 us; speedup 1.0000x reference)
//
#include <hip/hip_runtime.h>
#include <hip/hip_bf16.h>

typedef unsigned short u16;
typedef __attribute__((ext_vector_type(8))) short short8;
typedef __attribute__((ext_vector_type(4))) float floatx4;

#define TOKENS 8192
#define KDIM   2048
#define NFEAT  8192
#define R_     4
#define M1_    1024
#define N1_    2048
#define M2_    2
#define N2_    4

#define BM 128
#define BN 128
#define BK 64

__device__ __forceinline__ u16 f2bf(float f) {
  union { float f; unsigned u; } v; v.f = f;
  unsigned r = v.u + 0x7fffu + ((v.u >> 16) & 1u);  // RNE
  return (u16)(r >> 16);
}

// ---- P0: invert the permutation: pf[p_inv[c]] = c ----
__global__ void k_invert_perm(const int* __restrict__ p_inv, int* __restrict__ pf) {
  int i = blockIdx.x * 256 + threadIdx.x;
  if (i < KDIM) pf[p_inv[i]] = i;
}

// ---- P1: x (fp32) -> Xb (bf16), vectorized 4/thread ----
struct u16x4 { u16 a, b, c, d; };
__global__ void k_cvt_x(const float4* __restrict__ x4, u16x4* __restrict__ xb) {
  int i = blockIdx.x * 256 + threadIdx.x;   // exactly 16384*256 = 4.19M threads
  float4 v = x4[i];
  u16x4 o; o.a = f2bf(v.x); o.b = f2bf(v.y); o.c = f2bf(v.z); o.d = f2bf(v.w);
  xb[i] = o;
}

// ---- P2: fused weight Wf[f][k] = sum_r A[r, n, m1] * B[r, m2, j]
//      with c = pf[k], m1=c>>1, m2=c&1, n=q[f]>>2, j=q[f]&3 ----
__global__ void k_build_w(const float* __restrict__ A, const float* __restrict__ Bm,
                          const int* __restrict__ pf, const int* __restrict__ q,
                          u16* __restrict__ Wf) {
  int bid = blockIdx.x;                 // 8192 f * 8 k-chunks = 65536 blocks
  int f = bid >> 3;
  int k = (bid & 7) * 256 + threadIdx.x;
  int c = pf[k];
  int m1 = c >> 1, m2 = c & 1;
  int qf = q[f];
  int n = qf >> 2, j = qf & 3;
  float acc = 0.f;
#pragma unroll
  for (int r = 0; r < R_; ++r)
    acc += A[(size_t)r * (N1_ * M1_) + (size_t)n * M1_ + m1] * Bm[r * (M2_ * N2_) + m2 * N2_ + j];
  Wf[(size_t)f * KDIM + k] = f2bf(acc);
}

// ---- GEMM: out[t][f] = sum_k Xb[t][k] * Wf[f][k] + bias[f]
//      m97 structure: 128x128 tile, BK=64, 4 waves, global_load_lds width 16.
#define GLD16(gp, lp) __builtin_amdgcn_global_load_lds( \
    (const __attribute__((address_space(1))) void*)(gp), \
    (__attribute__((address_space(3))) void*)(lp), 16, 0, 0)

__global__ __launch_bounds__(256) void k_gemm(
    const u16* __restrict__ X, const u16* __restrict__ W,
    const float* __restrict__ bias, float* __restrict__ out) {
  __shared__ u16 As[BM * BK];   // 16 KB, rows = tokens, 64 k each
  __shared__ u16 Bs[BN * BK];   // 16 KB, rows = features

  // XCD-aware bijective swizzle (4096 % 8 == 0)
  int bid = blockIdx.x;
  int cpx = gridDim.x >> 3;                 // 512
  int wg  = (bid & 7) * cpx + (bid >> 3);
  int tM = wg >> 6;                         // 64 token tiles
  int tN = wg & 63;                         // 64 feature tiles
  size_t rowBase = (size_t)tM * BM;
  size_t colBase = (size_t)tN * BN;

  int tid  = threadIdx.x;
  int wave = tid >> 6, lane = tid & 63;
  int wr = wave >> 1, wc = wave & 1;        // 2x2 waves of 64x64 each

  // staging geometry: chunk c = 1KB = 8 rows x 64 k (bf16). Wave handles 4 chunks.
  int rowInChunk = lane >> 3;               // 0..7
  int kOff = (lane & 7) * 8;                // bf16 elements

  floatx4 acc[4][4] = {};

  for (int ks = 0; ks < KDIM; ks += BK) {
#pragma unroll
    for (int i = 0; i < 4; ++i) {
      int c = wave * 4 + i;
      int r = c * 8 + rowInChunk;
      GLD16(X + (rowBase + r) * KDIM + ks + kOff, &As[c * 512]);
      GLD16(W + (colBase + r) * KDIM + ks + kOff, &Bs[c * 512]);
    }
    __syncthreads();   // drains vmcnt(0) -> staged data visible

#pragma unroll
    for (int kk = 0; kk < BK; kk += 32) {
      short8 af[4], bf[4];
#pragma unroll
      for (int m = 0; m < 4; ++m)
        af[m] = *(const short8*)&As[(wr * 64 + m * 16 + (lane & 15)) * BK + kk + ((lane >> 4) * 8)];
#pragma unroll
      for (int n = 0; n < 4; ++n)
        bf[n] = *(const short8*)&Bs[(wc * 64 + n * 16 + (lane & 15)) * BK + kk + ((lane >> 4) * 8)];
#pragma unroll
      for (int m = 0; m < 4; ++m)
#pragma unroll
        for (int n = 0; n < 4; ++n)
          acc[m][n] = __builtin_amdgcn_mfma_f32_16x16x32_bf16(af[m], bf[n], acc[m][n], 0, 0, 0);
    }
    __syncthreads();
  }

  // epilogue: C/D layout col = lane&15, row = (lane>>4)*4 + reg  [m89/m91 verified]
  float bv[4];
#pragma unroll
  for (int n = 0; n < 4; ++n)
    bv[n] = bias[colBase + wc * 64 + n * 16 + (lane & 15)];
#pragma unroll
  for (int m = 0; m < 4; ++m) {
    int r0 = wr * 64 + m * 16 + ((lane >> 4) << 2);
#pragma unroll
    for (int n = 0; n < 4; ++n) {
      size_t base = (rowBase + r0) * (size_t)NFEAT + colBase + wc * 64 + n * 16 + (lane & 15);
#pragma unroll
      for (int reg = 0; reg < 4; ++reg)
        out[base + (size_t)reg * NFEAT] = acc[m][n][reg] + bv[n];
    }
  }
}

extern "C" void kernel_launch(void* const* d_in, const int* in_sizes, int n_in,
                              void* d_out, int out_size, void* d_ws, size_t ws_size,
                              hipStream_t stream) {
  const float* x     = (const float*)d_in[0];   // (4,2048,2048)
  const float* A     = (const float*)d_in[1];   // (4,2048,1024)
  const float* Bm    = (const float*)d_in[2];   // (4,2,4)
  const float* bias  = (const float*)d_in[3];   // (8192,)
  const int*   p_inv = (const int*)d_in[4];     // (2048,)
  const int*   q     = (const int*)d_in[5];     // (8192,)
  float* out = (float*)d_out;                   // (4,2048,8192)

  // workspace layout: Xb 32MB | Wf 32MB | pf 8KB   (needs >= 64MB + 8KB)
  u16* Xb = (u16*)d_ws;
  u16* Wf = (u16*)((char*)d_ws + (size_t)TOKENS * KDIM * 2);
  int* pf = (int*)((char*)d_ws + (size_t)TOKENS * KDIM * 2 * 2);

  k_invert_perm<<<(KDIM + 255) / 256, 256, 0, stream>>>(p_inv, pf);
  k_cvt_x<<<(TOKENS * KDIM / 4) / 256, 256, 0, stream>>>((const float4*)x, (u16x4*)Xb);
  k_build_w<<<NFEAT * (KDIM / 256), 256, 0, stream>>>(A, Bm, pf, q, Wf);
  k_gemm<<<(TOKENS / BM) * (NFEAT / BN), 256, 0, stream>>>(Xb, Wf, bias, out);
}

// Round 2
// 370.526 us; speedup vs baseline: 1.5369x; 1.5369x over previous
//
#include <hip/hip_runtime.h>
#include <hip/hip_bf16.h>

typedef unsigned short u16;
typedef __attribute__((ext_vector_type(8))) short short8;
typedef __attribute__((ext_vector_type(4))) float floatx4;

#define TOKENS 8192
#define KDIM   2048
#define NFEAT  8192
#define R_     4
#define N1_    2048
#define M1_    1024

#define BM 256
#define BN 128
#define BK 64
#define NSTEPS (KDIM / BK)     // 32
#define ABYTES (BM * BK * 2)   // 32768
#define BBYTES (BN * BK * 2)   // 16384
#define BUFB   (ABYTES + BBYTES) // 49152; 3 buffers = 144 KB LDS

__device__ __forceinline__ u16 f2bf(float f) {
  union { float f; unsigned u; } v; v.f = f;
  unsigned r = v.u + 0x7fffu + ((v.u >> 16) & 1u);  // RNE
  return (u16)(r >> 16);
}

// ---- P0: invert the permutation: pf[p_inv[c]] = c ----
__global__ void k_invert_perm(const int* __restrict__ p_inv, int* __restrict__ pf) {
  int i = blockIdx.x * 256 + threadIdx.x;
  if (i < KDIM) pf[p_inv[i]] = i;
}

// ---- P1: x (fp32) -> Xb (bf16), 4/thread ----
struct u16x4 { u16 a, b, c, d; };
__global__ void k_cvt_x(const float4* __restrict__ x4, u16x4* __restrict__ xb) {
  int i = blockIdx.x * 256 + threadIdx.x;
  float4 v = x4[i];
  u16x4 o; o.a = f2bf(v.x); o.b = f2bf(v.y); o.c = f2bf(v.z); o.d = f2bf(v.w);
  xb[i] = o;
}

// ---- P2: fused weight Wf[f][k] = sum_r A[r, q[f]>>2, pf[k]>>1] * B[r, pf[k]&1, q[f]&3]
//      8 k per thread, short8 (16B) stores.
__global__ void k_build_w(const float* __restrict__ A, const float* __restrict__ Bm,
                          const int* __restrict__ pf, const int* __restrict__ q,
                          u16* __restrict__ Wf) {
  int f = blockIdx.x;                  // 8192 blocks
  int k0 = threadIdx.x * 8;            // 256 threads x 8 k
  int qf = q[f];
  int n = qf >> 2, j = qf & 3;
  const float* An = A + (size_t)n * M1_;
  float bc[8];                          // Bm[r][m2][j]
#pragma unroll
  for (int r = 0; r < R_; ++r) {
    bc[r * 2 + 0] = Bm[r * 8 + 0 * 4 + j];
    bc[r * 2 + 1] = Bm[r * 8 + 1 * 4 + j];
  }
  u16 w[8];
#pragma unroll
  for (int i = 0; i < 8; ++i) {
    int c = pf[k0 + i];
    int m1 = c >> 1, m2 = c & 1;
    float acc = 0.f;
#pragma unroll
    for (int r = 0; r < R_; ++r)
      acc += An[(size_t)r * (N1_ * M1_) + m1] * bc[r * 2 + m2];
    w[i] = f2bf(acc);
  }
  *(short8*)(Wf + (size_t)f * KDIM + k0) = *(const short8*)w;
}

// ---- GEMM: out[t][f] = sum_k Xb[t][k] * Wf[f][k] + bias[f]
// 256x128 tile, BK=64, 8 waves (4M x 2N), 3-deep LDS pipeline, counted vmcnt(6),
// st-16B XOR swizzle (slot ^= row&7) on both stage-source and ds_read.
#define GLD16(gp, lp) __builtin_amdgcn_global_load_lds( \
    (const __attribute__((address_space(1))) void*)(gp), \
    (__attribute__((address_space(3))) void*)(lp), 16, 0, 0)

__global__ __launch_bounds__(512, 2) void k_gemm(
    const u16* __restrict__ X, const u16* __restrict__ W,
    const float* __restrict__ bias, float* __restrict__ out) {
  __shared__ __align__(16) char lds[3 * BUFB];   // 144 KB -> 1 block/CU, 2 waves/SIMD

  // XCD-aware bijective swizzle (2048 % 8 == 0)
  int bid = blockIdx.x;
  int wg  = (bid & 7) * (gridDim.x >> 3) + (bid >> 3);
  int tM = wg >> 6;                     // 0..31
  int tN = wg & 63;                     // 0..63
  int rowBase = tM * BM;
  int colBase = tN * BN;

  int tid  = threadIdx.x;
  int lane = tid & 63;
  int wave = tid >> 6;
  int wm = wave >> 1;                   // 0..3 : rows [wm*64, +64)
  int wn = wave & 1;                    // 0..1 : cols [wn*64, +64)

  // ---- staging geometry: per 8KB round, thread covers lds bytes tid*16.
  // lds row = (roundRow64)*64 + (tid>>3), slot = tid&7; source col = (slot ^ row&7)*8 elems.
  int srow = tid >> 3;                              // 0..63
  int scol = ((tid & 7) ^ (srow & 7)) * 8;          // pre-swizzled source col (bf16 elems)
  const u16* Asrc = X + (size_t)(rowBase + srow) * KDIM + scol;
  const u16* Bsrc = W + (size_t)(colBase + srow) * KDIM + scol;

  // ---- fragment read offsets (bytes): row*128 + (slot ^ (row&7))*16
  int fr   = lane & 15;
  int asl0 = ( (lane >> 4)      ^ (lane & 7)) * 16;  // kk=0 slot
  int asl1 = ((4 + (lane >> 4)) ^ (lane & 7)) * 16;  // kk=1 slot
  int aoff0 = (wm * 64 + fr) * 128 + asl0;
  int aoff1 = (wm * 64 + fr) * 128 + asl1;
  int boff0 = ABYTES + (wn * 64 + fr) * 128 + asl0;
  int boff1 = ABYTES + (wn * 64 + fr) * 128 + asl1;

  floatx4 acc[4][4] = {};

  auto STAGE = [&](int t) {
    unsigned sb = (unsigned)(t % 3) * BUFB;
    int ks = t * BK;
#pragma unroll
    for (int jj = 0; jj < 4; ++jj)      // A: 4 x 8KB rounds
      GLD16(Asrc + ks + (size_t)jj * 64 * KDIM, &lds[sb + jj * 8192 + tid * 16]);
#pragma unroll
    for (int jj = 0; jj < 2; ++jj)      // B: 2 x 8KB rounds
      GLD16(Bsrc + ks + (size_t)jj * 64 * KDIM, &lds[sb + ABYTES + jj * 8192 + tid * 16]);
  };

  auto COMPUTE = [&](int t) {
    const char* base = lds + (unsigned)(t % 3) * BUFB;
    short8 a[4][2], b[4][2];
#pragma unroll
    for (int m = 0; m < 4; ++m) {
      a[m][0] = *(const short8*)(base + aoff0 + m * 2048);
      a[m][1] = *(const short8*)(base + aoff1 + m * 2048);
    }
#pragma unroll
    for (int n = 0; n < 4; ++n) {
      b[n][0] = *(const short8*)(base + boff0 + n * 2048);
      b[n][1] = *(const short8*)(base + boff1 + n * 2048);
    }
    __builtin_amdgcn_s_setprio(1);
#pragma unroll
    for (int m = 0; m < 4; ++m)
#pragma unroll
      for (int n = 0; n < 4; ++n) {
        acc[m][n] = __builtin_amdgcn_mfma_f32_16x16x32_bf16(a[m][0], b[n][0], acc[m][n], 0, 0, 0);
        acc[m][n] = __builtin_amdgcn_mfma_f32_16x16x32_bf16(a[m][1], b[n][1], acc[m][n], 0, 0, 0);
      }
    __builtin_amdgcn_s_setprio(0);
  };

  // ---- prologue: fill 2 tiles, wait tile 0 (12 issued, keep 6 in flight)
  STAGE(0);
  STAGE(1);
  asm volatile("s_waitcnt vmcnt(6)" ::: "memory");
  __builtin_amdgcn_s_barrier();

  // ---- main loop: stage t+2 while computing t; vmcnt(6) leaves (t+2)'s 6 loads in flight
  for (int t = 0; t < NSTEPS - 2; ++t) {
    STAGE(t + 2);
    COMPUTE(t);
    asm volatile("s_waitcnt vmcnt(6)" ::: "memory");
    __builtin_amdgcn_s_barrier();
  }
  // ---- epilogue: drain
  COMPUTE(NSTEPS - 2);
  asm volatile("s_waitcnt vmcnt(0)" ::: "memory");
  __builtin_amdgcn_s_barrier();
  COMPUTE(NSTEPS - 1);

  // ---- C write: col = lane&15, row = (lane>>4)*4 + reg  [m89/m91 verified]
  float bv[4];
#pragma unroll
  for (int n = 0; n < 4; ++n)
    bv[n] = bias[colBase + wn * 64 + n * 16 + fr];
#pragma unroll
  for (int m = 0; m < 4; ++m) {
    int r0 = wm * 64 + m * 16 + ((lane >> 4) << 2);
#pragma unroll
    for (int n = 0; n < 4; ++n) {
      size_t basep = (size_t)(rowBase + r0) * NFEAT + colBase + wn * 64 + n * 16 + fr;
#pragma unroll
      for (int reg = 0; reg < 4; ++reg)
        out[basep + (size_t)reg * NFEAT] = acc[m][n][reg] + bv[n];
    }
  }
}

extern "C" void kernel_launch(void* const* d_in, const int* in_sizes, int n_in,
                              void* d_out, int out_size, void* d_ws, size_t ws_size,
                              hipStream_t stream) {
  const float* x     = (const float*)d_in[0];   // (4,2048,2048)
  const float* A     = (const float*)d_in[1];   // (4,2048,1024)
  const float* Bm    = (const float*)d_in[2];   // (4,2,4)
  const float* bias  = (const float*)d_in[3];   // (8192,)
  const int*   p_inv = (const int*)d_in[4];     // (2048,)
  const int*   q     = (const int*)d_in[5];     // (8192,)
  float* out = (float*)d_out;                   // (4,2048,8192)

  // workspace: Xb 32MB | Wf 32MB | pf 8KB
  u16* Xb = (u16*)d_ws;
  u16* Wf = (u16*)((char*)d_ws + (size_t)TOKENS * KDIM * 2);
  int* pf = (int*)((char*)d_ws + (size_t)TOKENS * KDIM * 2 * 2);

  k_invert_perm<<<(KDIM + 255) / 256, 256, 0, stream>>>(p_inv, pf);
  k_cvt_x<<<(TOKENS * KDIM / 4) / 256, 256, 0, stream>>>((const float4*)x, (u16x4*)Xb);
  k_build_w<<<NFEAT, 256, 0, stream>>>(A, Bm, pf, q, Wf);
  k_gemm<<<(TOKENS / BM) * (NFEAT / BN), 512, 0, stream>>>(Xb, Wf, bias, out);
}

// Round 3
// 346.798 us; speedup vs baseline: 1.6420x; 1.0684x over previous
//
#include <hip/hip_runtime.h>
#include <hip/hip_bf16.h>

typedef unsigned short u16;
typedef __attribute__((ext_vector_type(8))) short short8;
typedef __attribute__((ext_vector_type(4))) float floatx4;

#define TOKENS 8192
#define KDIM   2048
#define NFEAT  8192
#define R_     4
#define N1_    2048
#define M1_    1024

#define BM 256
#define BN 256
#define BK 64
#define NITER (KDIM / (2 * BK))   // 16 iterations, 2 K-tiles each

__device__ __forceinline__ u16 f2bf(float f) {
  union { float f; unsigned u; } v; v.f = f;
  unsigned r = v.u + 0x7fffu + ((v.u >> 16) & 1u);  // RNE
  return (u16)(r >> 16);
}

// ---- P0: invert permutation ----
__global__ void k_invert_perm(const int* __restrict__ p_inv, int* __restrict__ pf) {
  int i = blockIdx.x * 256 + threadIdx.x;
  if (i < KDIM) pf[p_inv[i]] = i;
}

// ---- P1: x fp32 -> bf16 ----
struct u16x4 { u16 a, b, c, d; };
__global__ void k_cvt_x(const float4* __restrict__ x4, u16x4* __restrict__ xb) {
  int i = blockIdx.x * 256 + threadIdx.x;
  float4 v = x4[i];
  u16x4 o; o.a = f2bf(v.x); o.b = f2bf(v.y); o.c = f2bf(v.z); o.d = f2bf(v.w);
  xb[i] = o;
}

// ---- P2: fused weight ----
__global__ void k_build_w(const float* __restrict__ A, const float* __restrict__ Bm,
                          const int* __restrict__ pf, const int* __restrict__ q,
                          u16* __restrict__ Wf) {
  int f = blockIdx.x;
  int k0 = threadIdx.x * 8;
  int qf = q[f];
  int n = qf >> 2, j = qf & 3;
  const float* An = A + (size_t)n * M1_;
  float bc[8];
#pragma unroll
  for (int r = 0; r < R_; ++r) {
    bc[r * 2 + 0] = Bm[r * 8 + 0 * 4 + j];
    bc[r * 2 + 1] = Bm[r * 8 + 1 * 4 + j];
  }
  u16 w[8];
#pragma unroll
  for (int i = 0; i < 8; ++i) {
    int c = pf[k0 + i];
    int m1 = c >> 1, m2 = c & 1;
    float acc = 0.f;
#pragma unroll
    for (int r = 0; r < R_; ++r)
      acc += An[(size_t)r * (N1_ * M1_) + m1] * bc[r * 2 + m2];
    w[i] = f2bf(acc);
  }
  *(short8*)(Wf + (size_t)f * KDIM + k0) = *(const short8*)w;
}

// ---- GEMM: 256x256 tile, BK=64, 8 waves (2Mx4N), 8-phase counted-vmcnt schedule.
#define GLD16(gp, lp) __builtin_amdgcn_global_load_lds( \
    (const __attribute__((address_space(1))) void*)(gp), \
    (__attribute__((address_space(3))) void*)(lp), 16, 0, 0)

#define HBAR  do { __builtin_amdgcn_sched_barrier(0); __builtin_amdgcn_s_barrier(); \
                   __builtin_amdgcn_sched_barrier(0); } while (0)
#define LGKM0 do { asm volatile("s_waitcnt lgkmcnt(0)" ::: "memory"); \
                   __builtin_amdgcn_sched_barrier(0); } while (0)
#define VMCNT(n) asm volatile("s_waitcnt vmcnt(" #n ")" ::: "memory")

__global__ __launch_bounds__(512, 2) void k_gemm(
    const u16* __restrict__ X, const u16* __restrict__ W,
    const float* __restrict__ bias, float* __restrict__ out) {
  // slot layout (64KB each, 2 slots = 128KB): A-half0 16K | A-half1 16K | B-half0 16K | B-half1 16K
  __shared__ __align__(16) char lds[2 * 65536];

  int bid = blockIdx.x;
  int wg  = (bid & 7) * (gridDim.x >> 3) + (bid >> 3);   // 1024 % 8 == 0 -> bijective
  int tM = wg >> 5, tN = wg & 31;
  int rowBase = tM * BM, colBase = tN * BN;

  int tid = threadIdx.x, lane = tid & 63, wave = tid >> 6;
  int wm = wave >> 2;                // 0..1 : rows [wm*128, +128)
  int wn = wave & 3;                 // 0..3 : cols [wn*64, +64)

  // staging: thread covers row srow (+64*jj +128*half), 16B slot (tid&7), pre-swizzled source
  int srow = tid >> 3;
  int scol = ((tid & 7) ^ (srow & 7)) * 8;
  const u16* Asrc = X + (size_t)(rowBase + srow) * KDIM + scol;
  const u16* Bsrc = W + (size_t)(colBase + srow) * KDIM + scol;

  auto SA = [&](int slot, int half, int kt) {
#pragma unroll
    for (int jj = 0; jj < 2; ++jj)
      GLD16(Asrc + (size_t)(half * 128 + jj * 64) * KDIM + kt * 64,
            &lds[slot * 65536 + half * 16384 + jj * 8192 + tid * 16]);
  };
  auto SB = [&](int slot, int half, int kt) {
#pragma unroll
    for (int jj = 0; jj < 2; ++jj)
      GLD16(Bsrc + (size_t)(half * 128 + jj * 64) * KDIM + kt * 64,
            &lds[slot * 65536 + 32768 + half * 16384 + jj * 8192 + tid * 16]);
  };

  // fragment read offsets: row*128 + ((kk*4 + lane>>4) ^ (lane&7))*16
  int l15 = lane & 15, lhi = lane >> 4, l7 = lane & 7;
  int x0 = (lhi ^ l7) * 16;
  int x1 = ((4 + lhi) ^ l7) * 16;
  int abase = wm * 16384 + l15 * 128;
  int bbase = 32768 + (wn >> 1) * 16384 + ((wn & 1) * 64 + l15) * 128;

  auto RA = [&](int slot, int m, int kk) -> short8 {
    return *(const short8*)&lds[slot * 65536 + abase + m * 2048 + (kk ? x1 : x0)];
  };
  auto RB = [&](int slot, int n, int kk) -> short8 {
    return *(const short8*)&lds[slot * 65536 + bbase + n * 2048 + (kk ? x1 : x0)];
  };

  floatx4 acc[8][4] = {};
  short8 a[4][2], a2[4][2], b[2][2], b2[2][2];

  auto MM = [&](short8 (&Af)[4][2], short8 (&Bf)[2][2], int mo, int no) {
    __builtin_amdgcn_s_setprio(1);
#pragma unroll
    for (int m = 0; m < 4; ++m)
#pragma unroll
      for (int n = 0; n < 2; ++n) {
        acc[mo + m][no + n] = __builtin_amdgcn_mfma_f32_16x16x32_bf16(Af[m][0], Bf[n][0], acc[mo + m][no + n], 0, 0, 0);
        acc[mo + m][no + n] = __builtin_amdgcn_mfma_f32_16x16x32_bf16(Af[m][1], Bf[n][1], acc[mo + m][no + n], 0, 0, 0);
      }
    __builtin_amdgcn_s_setprio(0);
  };

  // ---- prologue: tile0 -> slot0 (8 loads), tile1 A-halves -> slot1 (4 loads)
  SA(0, 0, 0); SA(0, 1, 0); SB(0, 0, 0); SB(0, 1, 0);
  SA(1, 0, 1); SA(1, 1, 1);
  VMCNT(4);                       // slot0 fully landed; slot1's 4 A-loads in flight
  HBAR;

  for (int it = 0; it < NITER; ++it) {
    int t0 = 2 * it;
    bool full = (it < NITER - 1);

    // ======== K-tile t0 (slot 0) ========
    // phase 1: (mh0,nh0) reads; stage B0[s1, t0+1]
#pragma unroll
    for (int m = 0; m < 4; ++m) { a[m][0] = RA(0, m, 0); a[m][1] = RA(0, m, 1); }
#pragma unroll
    for (int n = 0; n < 2; ++n) { b[n][0] = RB(0, n, 0); b[n][1] = RB(0, n, 1); }
    SB(1, 0, t0 + 1);
    HBAR; LGKM0;
    MM(a, b, 0, 0);
    HBAR;

    // phase 2: (mh1,nh0) reads a2; stage B1[s1, t0+1]
#pragma unroll
    for (int m = 0; m < 4; ++m) { a2[m][0] = RA(0, 4 + m, 0); a2[m][1] = RA(0, 4 + m, 1); }
    SB(1, 1, t0 + 1);
    HBAR; LGKM0;
    MM(a2, b, 4, 0);
    HBAR;

    // phase 3: (mh1,nh1) reads b2; stage A0[s0, t0+2]
#pragma unroll
    for (int n = 0; n < 2; ++n) { b2[n][0] = RB(0, 2 + n, 0); b2[n][1] = RB(0, 2 + n, 1); }
    if (full) SA(0, 0, t0 + 2);
    HBAR; LGKM0;
    MM(a2, b2, 4, 2);
    HBAR;

    // phase 4: (mh0,nh1) no reads; stage A1[s0, t0+2]; slot1 must land before phase 5
    if (full) SA(0, 1, t0 + 2);
    MM(a, b2, 0, 2);
    if (full) VMCNT(4); else VMCNT(0);
    HBAR;

    // ======== K-tile t0+1 (slot 1) ========
    // phase 5: reads; stage B0[s0, t0+2]
#pragma unroll
    for (int m = 0; m < 4; ++m) { a[m][0] = RA(1, m, 0); a[m][1] = RA(1, m, 1); }
#pragma unroll
    for (int n = 0; n < 2; ++n) { b[n][0] = RB(1, n, 0); b[n][1] = RB(1, n, 1); }
    if (full) SB(0, 0, t0 + 2);
    HBAR; LGKM0;
    MM(a, b, 0, 0);
    HBAR;

    // phase 6: reads a2; stage B1[s0, t0+2]
#pragma unroll
    for (int m = 0; m < 4; ++m) { a2[m][0] = RA(1, 4 + m, 0); a2[m][1] = RA(1, 4 + m, 1); }
    if (full) SB(0, 1, t0 + 2);
    HBAR; LGKM0;
    MM(a2, b, 4, 0);
    HBAR;

    // phase 7: reads b2; stage A0[s1, t0+3]
#pragma unroll
    for (int n = 0; n < 2; ++n) { b2[n][0] = RB(1, 2 + n, 0); b2[n][1] = RB(1, 2 + n, 1); }
    if (full) SA(1, 0, t0 + 3);
    HBAR; LGKM0;
    MM(a2, b2, 4, 2);
    HBAR;

    // phase 8: no reads; stage A1[s1, t0+3]; slot0 (t0+2) must land before next ph1
    if (full) SA(1, 1, t0 + 3);
    MM(a, b2, 0, 2);
    if (full) VMCNT(4);
    HBAR;
  }

  // ---- epilogue: C = acc + bias; C/D layout col=lane&15, row=(lane>>4)*4+reg
  float bv[4];
#pragma unroll
  for (int n = 0; n < 4; ++n)
    bv[n] = bias[colBase + wn * 64 + n * 16 + l15];
#pragma unroll
  for (int m = 0; m < 8; ++m) {
    int r0 = wm * 128 + m * 16 + (lhi << 2);
#pragma unroll
    for (int n = 0; n < 4; ++n) {
      size_t basep = (size_t)(rowBase + r0) * NFEAT + colBase + wn * 64 + n * 16 + l15;
#pragma unroll
      for (int reg = 0; reg < 4; ++reg)
        out[basep + (size_t)reg * NFEAT] = acc[m][n][reg] + bv[n];
    }
  }
}

extern "C" void kernel_launch(void* const* d_in, const int* in_sizes, int n_in,
                              void* d_out, int out_size, void* d_ws, size_t ws_size,
                              hipStream_t stream) {
  const float* x     = (const float*)d_in[0];
  const float* A     = (const float*)d_in[1];
  const float* Bm    = (const float*)d_in[2];
  const float* bias  = (const float*)d_in[3];
  const int*   p_inv = (const int*)d_in[4];
  const int*   q     = (const int*)d_in[5];
  float* out = (float*)d_out;

  u16* Xb = (u16*)d_ws;
  u16* Wf = (u16*)((char*)d_ws + (size_t)TOKENS * KDIM * 2);
  int* pf = (int*)((char*)d_ws + (size_t)TOKENS * KDIM * 2 * 2);

  k_invert_perm<<<(KDIM + 255) / 256, 256, 0, stream>>>(p_inv, pf);
  k_cvt_x<<<(TOKENS * KDIM / 4) / 256, 256, 0, stream>>>((const float4*)x, (u16x4*)Xb);
  k_build_w<<<NFEAT, 256, 0, stream>>>(A, Bm, pf, q, Wf);
  k_gemm<<<(TOKENS / BM) * (NFEAT / BN), 512, 0, stream>>>(Xb, Wf, bias, out);
}

// Round 4
// 333.195 us; speedup vs baseline: 1.7090x; 1.0408x over previous
//
#include <hip/hip_runtime.h>
#include <hip/hip_bf16.h>

typedef unsigned short u16;
typedef __attribute__((ext_vector_type(8))) short short8;
typedef __attribute__((ext_vector_type(4))) float floatx4;

#define TOKENS 8192
#define KDIM   2048
#define NFEAT  8192
#define R_     4
#define N1_    2048
#define M1_    1024

#define BM 256
#define BN 256
#define BK 64
#define NITER (KDIM / (2 * BK))   // 16 iterations, 2 K-tiles each

__device__ __forceinline__ u16 f2bf(float f) {
  union { float f; unsigned u; } v; v.f = f;
  unsigned r = v.u + 0x7fffu + ((v.u >> 16) & 1u);  // RNE
  return (u16)(r >> 16);
}

// ---- P0: invert permutation ----
__global__ void k_invert_perm(const int* __restrict__ p_inv, int* __restrict__ pf) {
  int i = blockIdx.x * 256 + threadIdx.x;
  if (i < KDIM) pf[p_inv[i]] = i;
}

// ---- P1: x fp32 -> bf16 ----
struct u16x4 { u16 a, b, c, d; };
__global__ void k_cvt_x(const float4* __restrict__ x4, u16x4* __restrict__ xb) {
  int i = blockIdx.x * 256 + threadIdx.x;
  float4 v = x4[i];
  u16x4 o; o.a = f2bf(v.x); o.b = f2bf(v.y); o.c = f2bf(v.z); o.d = f2bf(v.w);
  xb[i] = o;
}

// ---- P2: fused weight Wf[f][k] ----
__global__ void k_build_w(const float* __restrict__ A, const float* __restrict__ Bm,
                          const int* __restrict__ pf, const int* __restrict__ q,
                          u16* __restrict__ Wf) {
  int f = blockIdx.x;
  int k0 = threadIdx.x * 8;
  int qf = q[f];
  int n = qf >> 2, j = qf & 3;
  const float* An = A + (size_t)n * M1_;
  float bc[8];
#pragma unroll
  for (int r = 0; r < R_; ++r) {
    bc[r * 2 + 0] = Bm[r * 8 + 0 * 4 + j];
    bc[r * 2 + 1] = Bm[r * 8 + 1 * 4 + j];
  }
  int4 c0 = *(const int4*)(pf + k0);
  int4 c1 = *(const int4*)(pf + k0 + 4);
  int cs[8] = {c0.x, c0.y, c0.z, c0.w, c1.x, c1.y, c1.z, c1.w};
  u16 w[8];
#pragma unroll
  for (int i = 0; i < 8; ++i) {
    int m1 = cs[i] >> 1, m2 = cs[i] & 1;
    float acc = 0.f;
#pragma unroll
    for (int r = 0; r < R_; ++r)
      acc += An[(size_t)r * (N1_ * M1_) + m1] * bc[r * 2 + m2];
    w[i] = f2bf(acc);
  }
  *(short8*)(Wf + (size_t)f * KDIM + k0) = *(const short8*)w;
}

// ---- GEMM: 256x256, BK=64, 8 waves (2Mx4N), 8-phase, read-ahead pipeline,
//      counted vmcnt(2) at ph3/ph7, light fences only (no sched_barrier).
#define GLD16(gp, lp) __builtin_amdgcn_global_load_lds( \
    (const __attribute__((address_space(1))) void*)(gp), \
    (__attribute__((address_space(3))) void*)(lp), 16, 0, 0)

#define FENCE asm volatile("" ::: "memory")
#define BAR   do { FENCE; __builtin_amdgcn_s_barrier(); FENCE; } while (0)
#define LGKM0 asm volatile("s_waitcnt lgkmcnt(0)" ::: "memory")
#define VMCNT(n) asm volatile("s_waitcnt vmcnt(" #n ")" ::: "memory")

__global__ __launch_bounds__(512, 2) void k_gemm(
    const u16* __restrict__ X, const u16* __restrict__ W,
    const float* __restrict__ bias, float* __restrict__ out) {
  // slot (64KB x2): A-half0 16K | A-half1 16K | B-half0 16K | B-half1 16K
  __shared__ __align__(16) char lds[2 * 65536];

  int bid = blockIdx.x;
  int wg  = (bid & 7) * (gridDim.x >> 3) + (bid >> 3);   // 1024 % 8 == 0 -> bijective
  int tM = wg >> 5, tN = wg & 31;
  int rowBase = tM * BM, colBase = tN * BN;

  int tid = threadIdx.x, lane = tid & 63, wave = tid >> 6;
  int wm = wave >> 2;                // 0..1 : rows [wm*128, +128)
  int wn = wave & 3;                 // 0..3 : cols [wn*64, +64)

  // staging: pre-swizzled global source, linear LDS dest (both-sides involution)
  int srow = tid >> 3;
  int scol = ((tid & 7) ^ (srow & 7)) * 8;
  const u16* Asrc = X + (size_t)(rowBase + srow) * KDIM + scol;
  const u16* Bsrc = W + (size_t)(colBase + srow) * KDIM + scol;

  auto SA = [&](int slot, int half, int kt) {
#pragma unroll
    for (int jj = 0; jj < 2; ++jj)
      GLD16(Asrc + (size_t)(half * 128 + jj * 64) * KDIM + kt * 64,
            &lds[slot * 65536 + half * 16384 + jj * 8192 + tid * 16]);
  };
  auto SB = [&](int slot, int half, int kt) {
#pragma unroll
    for (int jj = 0; jj < 2; ++jj)
      GLD16(Bsrc + (size_t)(half * 128 + jj * 64) * KDIM + kt * 64,
            &lds[slot * 65536 + 32768 + half * 16384 + jj * 8192 + tid * 16]);
  };

  // fragment reads: row*128 + ((kk*4 + lane>>4) ^ (lane&7))*16
  int l15 = lane & 15, lhi = lane >> 4, l7 = lane & 7;
  int x0 = (lhi ^ l7) * 16;
  int x1 = ((4 + lhi) ^ l7) * 16;
  int abase = wm * 16384 + l15 * 128;
  int bbase = 32768 + (wn >> 1) * 16384 + ((wn & 1) * 64 + l15) * 128;

  auto RA = [&](int slot, int m, int kk) -> short8 {
    return *(const short8*)&lds[slot * 65536 + abase + m * 2048 + (kk ? x1 : x0)];
  };
  auto RB = [&](int slot, int n, int kk) -> short8 {
    return *(const short8*)&lds[slot * 65536 + bbase + n * 2048 + (kk ? x1 : x0)];
  };

  floatx4 acc[8][4] = {};
  short8 a[4][2], a2[4][2], b[2][2], b2[2][2];

  auto RDa = [&](int slot) {
#pragma unroll
    for (int m = 0; m < 4; ++m) { a[m][0] = RA(slot, m, 0); a[m][1] = RA(slot, m, 1); }
  };
  auto RDa2 = [&](int slot) {
#pragma unroll
    for (int m = 0; m < 4; ++m) { a2[m][0] = RA(slot, 4 + m, 0); a2[m][1] = RA(slot, 4 + m, 1); }
  };
  auto RDb = [&](int slot) {
#pragma unroll
    for (int n = 0; n < 2; ++n) { b[n][0] = RB(slot, n, 0); b[n][1] = RB(slot, n, 1); }
  };
  auto RDb2 = [&](int slot) {
#pragma unroll
    for (int n = 0; n < 2; ++n) { b2[n][0] = RB(slot, 2 + n, 0); b2[n][1] = RB(slot, 2 + n, 1); }
  };

  auto MM = [&](short8 (&Af)[4][2], short8 (&Bf)[2][2], int mo, int no) {
    __builtin_amdgcn_s_setprio(1);
#pragma unroll
    for (int m = 0; m < 4; ++m)
#pragma unroll
      for (int n = 0; n < 2; ++n) {
        acc[mo + m][no + n] = __builtin_amdgcn_mfma_f32_16x16x32_bf16(Af[m][0], Bf[n][0], acc[mo + m][no + n], 0, 0, 0);
        acc[mo + m][no + n] = __builtin_amdgcn_mfma_f32_16x16x32_bf16(Af[m][1], Bf[n][1], acc[mo + m][no + n], 0, 0, 0);
      }
    __builtin_amdgcn_s_setprio(0);
  };

  // ---- prologue: slot0 = tile0 (8 loads), slot1-A = tile1 (4 loads in flight)
  SA(0, 0, 0); SA(0, 1, 0); SB(0, 0, 0); SB(0, 1, 0);
  SA(1, 0, 1); SA(1, 1, 1);
  VMCNT(4);                 // slot0's 8 landed; SA(1,*) 4 in flight
  BAR;
  RDa(0); RDb(0);           // q00 fragments for ph1

  for (int it = 0; it < NITER - 1; ++it) {
    int t0 = 2 * it;
    // ph1: MFMA q00(s0); read a2(s0) for ph2; stage SB(1,0,t0+1)
    LGKM0;
    RDa2(0); SB(1, 0, t0 + 1);
    MM(a, b, 0, 0);
    BAR;
    // ph2: MFMA q10; read b2(s0); stage SB(1,1,t0+1)
    LGKM0;
    RDb2(0); SB(1, 1, t0 + 1);
    MM(a2, b, 4, 0);
    BAR;
    // ph3: MFMA q11; stage SA(0,0,t0+2); publish slot1 (vmcnt oldest 8)
    LGKM0;
    SA(0, 0, t0 + 2);
    MM(a2, b2, 4, 2);
    VMCNT(2);
    BAR;
    // ph4: MFMA q01; read a,b (s1) for ph5; stage SA(0,1,t0+2)
    LGKM0;
    SA(0, 1, t0 + 2);
    MM(a, b2, 0, 2);
    RDa(1); RDb(1);
    BAR;
    // ph5: MFMA q00(s1); read a2(s1); stage SB(0,0,t0+2)
    LGKM0;
    RDa2(1); SB(0, 0, t0 + 2);
    MM(a, b, 0, 0);
    BAR;
    // ph6: MFMA q10; read b2(s1); stage SB(0,1,t0+2)
    LGKM0;
    RDb2(1); SB(0, 1, t0 + 2);
    MM(a2, b, 4, 0);
    BAR;
    // ph7: MFMA q11; stage SA(1,0,t0+3); publish slot0 t0+2
    LGKM0;
    SA(1, 0, t0 + 3);
    MM(a2, b2, 4, 2);
    VMCNT(2);
    BAR;
    // ph8: MFMA q01; read a,b (s0, t0+2) for next ph1; stage SA(1,1,t0+3)
    LGKM0;
    SA(1, 1, t0 + 3);
    MM(a, b2, 0, 2);
    RDa(0); RDb(0);
    BAR;
  }

  // ---- tail iteration (t0 = KDIM/64 - 2): no next-tile staging
  {
    int t0 = 2 * (NITER - 1);
    LGKM0; RDa2(0); SB(1, 0, t0 + 1); MM(a, b, 0, 0); BAR;
    LGKM0; RDb2(0); SB(1, 1, t0 + 1); MM(a2, b, 4, 0); BAR;
    LGKM0; MM(a2, b2, 4, 2); VMCNT(0); BAR;   // publish slot1 (all 8 drained)
    LGKM0; MM(a, b2, 0, 2); RDa(1); RDb(1);
    LGKM0; RDa2(1); MM(a, b, 0, 0);
    LGKM0; RDb2(1); MM(a2, b, 4, 0);
    LGKM0; MM(a2, b2, 4, 2);
    MM(a, b2, 0, 2);
  }

  // ---- epilogue: C = acc + bias; C/D layout col=lane&15, row=(lane>>4)*4+reg
  float bv[4];
#pragma unroll
  for (int n = 0; n < 4; ++n)
    bv[n] = bias[colBase + wn * 64 + n * 16 + l15];
#pragma unroll
  for (int m = 0; m < 8; ++m) {
    int r0 = wm * 128 + m * 16 + (lhi << 2);
#pragma unroll
    for (int n = 0; n < 4; ++n) {
      size_t basep = (size_t)(rowBase + r0) * NFEAT + colBase + wn * 64 + n * 16 + l15;
#pragma unroll
      for (int reg = 0; reg < 4; ++reg)
        out[basep + (size_t)reg * NFEAT] = acc[m][n][reg] + bv[n];
    }
  }
}

extern "C" void kernel_launch(void* const* d_in, const int* in_sizes, int n_in,
                              void* d_out, int out_size, void* d_ws, size_t ws_size,
                              hipStream_t stream) {
  const float* x     = (const float*)d_in[0];
  const float* A     = (const float*)d_in[1];
  const float* Bm    = (const float*)d_in[2];
  const float* bias  = (const float*)d_in[3];
  const int*   p_inv = (const int*)d_in[4];
  const int*   q     = (const int*)d_in[5];
  float* out = (float*)d_out;

  u16* Xb = (u16*)d_ws;
  u16* Wf = (u16*)((char*)d_ws + (size_t)TOKENS * KDIM * 2);
  int* pf = (int*)((char*)d_ws + (size_t)TOKENS * KDIM * 2 * 2);

  k_invert_perm<<<(KDIM + 255) / 256, 256, 0, stream>>>(p_inv, pf);
  k_cvt_x<<<(TOKENS * KDIM / 4) / 256, 256, 0, stream>>>((const float4*)x, (u16x4*)Xb);
  k_build_w<<<NFEAT, 256, 0, stream>>>(A, Bm, pf, q, Wf);
  k_gemm<<<(TOKENS / BM) * (NFEAT / BN), 512, 0, stream>>>(Xb, Wf, bias, out);
}